// Round 7
// baseline (845.811 us; speedup 1.0000x reference)
//
#include <hip/hip_runtime.h>
#include <hip/hip_bf16.h>
#include <cstdint>
#include <cstddef>

#define N_NODES 100000
#define N_PAD   100096   // 782 * 128, M padded to block tile
#define D 256

typedef __attribute__((ext_vector_type(8))) short short8;   // 8 bf16 = 4 VGPRs
typedef __attribute__((ext_vector_type(4))) float f32x4;

__device__ __forceinline__ float bf2f_lo(unsigned int u) {
    unsigned int x = u << 16;
    float f; __builtin_memcpy(&f, &x, 4); return f;
}
__device__ __forceinline__ float bf2f_hi(unsigned int u) {
    unsigned int x = u & 0xFFFF0000u;
    float f; __builtin_memcpy(&f, &x, 4); return f;
}
__device__ __forceinline__ unsigned short f2bf(float f) {
    unsigned int x; __builtin_memcpy(&x, &f, 4);
    unsigned int r = (x + 0x7FFFu + ((x >> 16) & 1u)) >> 16;   // RNE
    return (unsigned short)r;
}

// ---------------- CSR build ----------------

__global__ __launch_bounds__(256) void count_deg(const int* __restrict__ ei,
                                                 int* __restrict__ deg, int E) {
    int e = blockIdx.x * 256 + threadIdx.x;
    if (e < E) atomicAdd(&deg[ei[E + e]], 1);
}

// scan1 also produces dinv (folded former deg_inv_k launch)
__global__ __launch_bounds__(256) void scan1(const int* __restrict__ deg,
                                             int* __restrict__ rowstart,
                                             int* __restrict__ bsums,
                                             float* __restrict__ dinv, int N) {
    __shared__ int s[256];
    int i = blockIdx.x * 256 + threadIdx.x;
    int v = (i < N) ? deg[i] : 0;
    if (i < N) dinv[i] = 1.0f / fmaxf((float)v, 1.0f);
    s[threadIdx.x] = v;
    __syncthreads();
    for (int d = 1; d < 256; d <<= 1) {
        int t = (threadIdx.x >= d) ? s[threadIdx.x - d] : 0;
        __syncthreads();
        s[threadIdx.x] += t;
        __syncthreads();
    }
    if (i < N) rowstart[i] = s[threadIdx.x] - v;
    if (threadIdx.x == 255) bsums[blockIdx.x] = s[255];
}

// parallel one-block exclusive scan of bsums (nb <= 512), 256 threads x 2 elems
__global__ __launch_bounds__(256) void scan2p(int* __restrict__ bsums, int nb) {
    __shared__ int s[256];
    int t = threadIdx.x;
    int base = t * 2;
    int v0 = (base < nb) ? bsums[base] : 0;
    int v1 = (base + 1 < nb) ? bsums[base + 1] : 0;
    int sum = v0 + v1;
    s[t] = sum;
    __syncthreads();
    for (int d = 1; d < 256; d <<= 1) {
        int tv = (t >= d) ? s[t - d] : 0;
        __syncthreads();
        s[t] += tv;
        __syncthreads();
    }
    int excl = s[t] - sum;
    if (base < nb) bsums[base] = excl;
    if (base + 1 < nb) bsums[base + 1] = excl + v0;
}

__global__ __launch_bounds__(256) void scan3(int* __restrict__ rowstart,
                                             const int* __restrict__ bsums, int N) {
    int i = blockIdx.x * 256 + threadIdx.x;
    if (i < N) rowstart[i] += bsums[blockIdx.x];
}

__global__ __launch_bounds__(256) void fill_csr(const int* __restrict__ ei,
                                                const int* __restrict__ rowstart,
                                                int* __restrict__ cursor,
                                                int* __restrict__ csr, int E) {
    int e = blockIdx.x * 256 + threadIdx.x;
    if (e < E) {
        int src = ei[e], dst = ei[E + e];
        int slot = atomicAdd(&cursor[dst], 1);
        csr[rowstart[dst] + slot] = src;
    }
}

// ---------------- dtype prep ----------------

// covers N_PAD rows: rows >= N_NODES are zero-filled (replaces pad memset)
__global__ __launch_bounds__(256) void cvt_bf16(const float* __restrict__ src,
                                                unsigned short* __restrict__ dst,
                                                size_t n4, size_t nsrc4) {
    size_t i = (size_t)blockIdx.x * 256 + threadIdx.x;
    if (i >= n4) return;
    ushort4 o = {0, 0, 0, 0};
    if (i < nsrc4) {
        float4 v = *(const float4*)(src + i * 4);
        o.x = f2bf(v.x); o.y = f2bf(v.y); o.z = f2bf(v.z); o.w = f2bf(v.w);
    }
    *(ushort4*)(dst + i * 4) = o;
}

// W [K=256][N=256] f32 -> fragment-ordered bf16, 5 matrices in one launch.
// Wf[(kc*16 + ct)*64 + lane] = 8 bf16: B[k = kc*32 + (lane>>4)*8 + j][n = ct*16 + (lane&15)]
struct WP {
    const float* w[5];
    unsigned short* wf[5];
};
__global__ __launch_bounds__(64) void wfrag_prep(WP wp) {
    const float* __restrict__ W = wp.w[blockIdx.y];
    unsigned short* __restrict__ Wf = wp.wf[blockIdx.y];
    int g = blockIdx.x;              // 0..127: kc*16 + ct
    int lane = threadIdx.x;
    int m = lane & 15, q = lane >> 4;
    int ct = g & 15, kc = g >> 4;
    int n = ct * 16 + m;
    int k0 = kc * 32 + q * 8;
    unsigned short v[8];
#pragma unroll
    for (int j = 0; j < 8; j++) v[j] = f2bf(W[(size_t)(k0 + j) * D + n]);
    *(short8*)(Wf + ((size_t)g * 64 + lane) * 8) = *(short8*)v;
}

// ---------------- fused mean-aggregate + SAGE conv ----------------
// Each block owns 128 output rows. Phase 1: the block's 4 waves gather the
// mean-aggregated neighbor features for their 32 nodes each (proven paired-row
// full-wave gather: lanes 0-31 row sA, 32-63 row sB, 1 KB/instr) and ds_write
// the bf16 means into a 64 KB LDS Am tile (XOR-swizzled: unit' = unit^(row&15),
// same involution on write and read -> conflict-free fragment reads).
// Phase 2 (after ONE barrier): barrier-free GEMM. A-fragments: kc<8 from LDS
// (Am), kc>=8 from global (X = same buffer as gather source). B-fragments read
// DIRECTLY from global Wf (256 KB, L2-hot; no LDS staging -> LDS stays 64 KB,
// 2 blocks/CU). Gather is bound by the ~3.8 TB/s random-gather serving tier
// (invariant to MLP, r0 vs r3); the GEMM's MFMA + L2-W reads ride under it via
// cross-block overlap.

__device__ __forceinline__ void acc8(float* acc, uint4 v) {
    acc[0] += bf2f_lo(v.x); acc[1] += bf2f_hi(v.x);
    acc[2] += bf2f_lo(v.y); acc[3] += bf2f_hi(v.y);
    acc[4] += bf2f_lo(v.z); acc[5] += bf2f_hi(v.z);
    acc[6] += bf2f_lo(v.w); acc[7] += bf2f_hi(v.w);
}

__global__ __launch_bounds__(256, 2) void fused_conv(const unsigned short* __restrict__ Xb,
                                                     const int* __restrict__ csr,
                                                     const int* __restrict__ rowstart,
                                                     const int* __restrict__ deg,
                                                     const float* __restrict__ dinv,
                                                     const unsigned short* __restrict__ Wf,
                                                     const float* __restrict__ bias,
                                                     unsigned short* __restrict__ outb) {
    __shared__ unsigned short am[128 * 256];   // 64 KB swizzled mean tile
    int tid = threadIdx.x;
    int lane = tid & 63;
    int wid = tid >> 6;
    int l = lane;
    int hi = l >> 5;
    int voff = (l & 31) * 8;
    const unsigned short* xb = Xb + voff;

    // ---- phase 1: gather means for this wave's 32 nodes ----
    for (int n = 0; n < 32; n++) {
        int rw = wid * 32 + n;                      // row within tile, 0..127
        int node = blockIdx.x * 128 + rw;           // wave-uniform
        int start = 0, cnt = 0;
        if (node < N_NODES) {
            start = __builtin_amdgcn_readfirstlane(rowstart[node]);
            cnt   = __builtin_amdgcn_readfirstlane(deg[node]);
        }
        float acc[8];
#pragma unroll
        for (int i = 0; i < 8; i++) acc[i] = 0.f;

        int j = 0;
        for (; j + 16 <= cnt; j += 16) {
            uint4 v[8];
#pragma unroll
            for (int p = 0; p < 8; p++) {
                int sA = csr[start + j + 2 * p];
                int sB = csr[start + j + 2 * p + 1];
                int s = hi ? sB : sA;
                v[p] = *(const uint4*)(xb + (size_t)s * D);
            }
#pragma unroll
            for (int p = 0; p < 8; p++) acc8(acc, v[p]);
        }
        int cm1 = (cnt > 0) ? (cnt - 1) : 0;
        for (; j < cnt; j += 8) {
            uint4 v[4];
#pragma unroll
            for (int p = 0; p < 4; p++) {
                int i0 = j + 2 * p;
                int i1 = i0 + 1;
                int sA = csr[start + (i0 < cnt ? i0 : cm1)];
                int sB = csr[start + (i1 < cnt ? i1 : cm1)];
                sA = (i0 < cnt) ? sA : N_NODES;     // row N_NODES is all-zero
                sB = (i1 < cnt) ? sB : N_NODES;
                int s = hi ? sB : sA;
                v[p] = *(const uint4*)(xb + (size_t)s * D);
            }
#pragma unroll
            for (int p = 0; p < 4; p++) acc8(acc, v[p]);
        }
#pragma unroll
        for (int i = 0; i < 8; i++) acc[i] += __shfl_xor(acc[i], 32);
        if (l < 32) {
            float s = (node < N_NODES) ? dinv[node] : 0.f;
            uint4 o;
            o.x = (unsigned int)f2bf(acc[0] * s) | ((unsigned int)f2bf(acc[1] * s) << 16);
            o.y = (unsigned int)f2bf(acc[2] * s) | ((unsigned int)f2bf(acc[3] * s) << 16);
            o.z = (unsigned int)f2bf(acc[4] * s) | ((unsigned int)f2bf(acc[5] * s) << 16);
            o.w = (unsigned int)f2bf(acc[6] * s) | ((unsigned int)f2bf(acc[7] * s) << 16);
            int unit = l ^ (rw & 15);               // XOR swizzle (write side)
            *(uint4*)(am + (size_t)rw * 256 + unit * 8) = o;
        }
    }
    __syncthreads();   // all means in LDS; GEMM phase is barrier-free

    // ---- phase 2: GEMM  out = relu([Am | X] @ Wf + b) ----
    int m = lane & 15, q = lane >> 4;
    int wrr = wid >> 1, wc = wid & 1;               // 2x2 wave grid, 64x128 tiles
    int rowb = blockIdx.x * 128 + wrr * 64;
    int ctb = wc * 8;

    f32x4 acc2[4][8];
#pragma unroll
    for (int f = 0; f < 4; f++)
#pragma unroll
        for (int ct = 0; ct < 8; ct++) acc2[f][ct] = (f32x4){0.f, 0.f, 0.f, 0.f};

    // kc 0..7: A from LDS Am (swizzled read)
    for (int kc = 0; kc < 8; kc++) {
        short8 a[4];
#pragma unroll
        for (int f = 0; f < 4; f++) {
            int rw = wrr * 64 + f * 16 + m;         // rw & 15 == m
            int unit = (kc * 4 + q) ^ m;            // XOR swizzle (read side)
            a[f] = *(const short8*)(am + (size_t)rw * 256 + unit * 8);
        }
#pragma unroll
        for (int ct = 0; ct < 8; ct++) {
            short8 b = *(const short8*)(Wf + ((size_t)(kc * 16 + ctb + ct) * 64 + lane) * 8);
#pragma unroll
            for (int f = 0; f < 4; f++)
                acc2[f][ct] = __builtin_amdgcn_mfma_f32_16x16x32_bf16(a[f], b, acc2[f][ct], 0, 0, 0);
        }
    }
    // kc 8..15: A = X from global (the gather-source buffer)
    for (int kc = 8; kc < 16; kc++) {
        int koff = (kc & 7) * 32 + q * 8;
        short8 a[4];
#pragma unroll
        for (int f = 0; f < 4; f++)
            a[f] = *(const short8*)(Xb + (size_t)(rowb + f * 16 + m) * D + koff);
#pragma unroll
        for (int ct = 0; ct < 8; ct++) {
            short8 b = *(const short8*)(Wf + ((size_t)(kc * 16 + ctb + ct) * 64 + lane) * 8);
#pragma unroll
            for (int f = 0; f < 4; f++)
                acc2[f][ct] = __builtin_amdgcn_mfma_f32_16x16x32_bf16(a[f], b, acc2[f][ct], 0, 0, 0);
        }
    }

#pragma unroll
    for (int f = 0; f < 4; f++)
#pragma unroll
        for (int ct = 0; ct < 8; ct++) {
            float bb = bias[(ctb + ct) * 16 + m];
#pragma unroll
            for (int r = 0; r < 4; r++) {
                int row = rowb + f * 16 + q * 4 + r;
                float v = acc2[f][ct][r] + bb;
                // pad rows get exact zeros (next layer's gather reads row N_NODES)
                outb[(size_t)row * D + (ctb + ct) * 16 + m] =
                    (row < N_NODES) ? f2bf(fmaxf(v, 0.f)) : (unsigned short)0;
            }
        }
}

// final linear: out = A @ Wf + b, f32 out, store-guarded, no relu.
// Barrier-free: A rows from global (each read once per kc), B direct from
// global Wf (L2-hot). No LDS at all.
__global__ __launch_bounds__(256, 2) void lin_mfma(const unsigned short* __restrict__ A,
                                                   const unsigned short* __restrict__ Wf,
                                                   const float* __restrict__ bias,
                                                   float* __restrict__ out) {
    int tid = threadIdx.x;
    int lane = tid & 63;
    int m = lane & 15, q = lane >> 4;
    int wid = tid >> 6;
    int wrr = wid >> 1, wc = wid & 1;
    int rowb = blockIdx.x * 128 + wrr * 64;
    int ctb = wc * 8;

    f32x4 acc[4][8];
#pragma unroll
    for (int f = 0; f < 4; f++)
#pragma unroll
        for (int ct = 0; ct < 8; ct++) acc[f][ct] = (f32x4){0.f, 0.f, 0.f, 0.f};

    for (int kc = 0; kc < 8; kc++) {
        int koff = kc * 32 + q * 8;
        short8 a[4];
#pragma unroll
        for (int f = 0; f < 4; f++)
            a[f] = *(const short8*)(A + (size_t)(rowb + f * 16 + m) * D + koff);
#pragma unroll
        for (int ct = 0; ct < 8; ct++) {
            short8 b = *(const short8*)(Wf + ((size_t)(kc * 16 + ctb + ct) * 64 + lane) * 8);
#pragma unroll
            for (int f = 0; f < 4; f++)
                acc[f][ct] = __builtin_amdgcn_mfma_f32_16x16x32_bf16(a[f], b, acc[f][ct], 0, 0, 0);
        }
    }
#pragma unroll
    for (int f = 0; f < 4; f++)
#pragma unroll
        for (int ct = 0; ct < 8; ct++) {
            float bb = bias[(ctb + ct) * 16 + m];
#pragma unroll
            for (int r = 0; r < 4; r++) {
                int row = rowb + f * 16 + q * 4 + r;
                if (row < N_NODES)
                    out[(size_t)row * D + (ctb + ct) * 16 + m] = acc[f][ct][r] + bb;
            }
        }
}

// ---------------- launch ----------------

extern "C" void kernel_launch(void* const* d_in, const int* in_sizes, int n_in,
                              void* d_out, int out_size, void* d_ws, size_t ws_size,
                              hipStream_t stream) {
    const float* x   = (const float*)d_in[0];
    const int*   ei  = (const int*)d_in[1];
    const float* W1l = (const float*)d_in[2];
    const float* b1  = (const float*)d_in[3];
    const float* W1r = (const float*)d_in[4];
    const float* W2l = (const float*)d_in[5];
    const float* b2  = (const float*)d_in[6];
    const float* W2r = (const float*)d_in[7];
    const float* W3  = (const float*)d_in[8];
    const float* b3  = (const float*)d_in[9];
    float* out = (float*)d_out;

    const int N = N_NODES;
    const int E = in_sizes[1] / 2;
    const size_t FB = (size_t)N_PAD * D * sizeof(unsigned short);   // 51.25 MB
    const size_t WFRAG = (size_t)128 * 64 * 8;   // shorts per 256-K half

    char* p = (char*)d_ws;
    unsigned short* B1 = (unsigned short*)p; p += FB;   // xb, then conv2 out (h2)
    unsigned short* B3 = (unsigned short*)p; p += FB;   // conv1 out (h1)
    unsigned short* Wf1 = (unsigned short*)p; p += WFRAG * 2 * 2;   // [W1l | W1r] frag
    unsigned short* Wf2 = (unsigned short*)p; p += WFRAG * 2 * 2;
    unsigned short* Wf3 = (unsigned short*)p; p += WFRAG * 2;
    int*   deg      = (int*)p;   p += (size_t)N * 4;
    int*   cursor   = (int*)p;   p += (size_t)N * 4;   // adjacent to deg: one memset
    float* dinv     = (float*)p; p += (size_t)N * 4;
    int*   rowstart = (int*)p;   p += (size_t)N * 4;
    int*   bsums    = (int*)p;   p += 4096;
    int*   csr      = (int*)p;   p += (size_t)E * 4;

    hipMemsetAsync(deg, 0, (size_t)N * 8, stream);   // deg + cursor in one shot

    int ebl = (E + 255) / 256;
    int nbl = (N + 255) / 256;

    // CSR
    count_deg<<<ebl, 256, 0, stream>>>(ei, deg, E);
    scan1<<<nbl, 256, 0, stream>>>(deg, rowstart, bsums, dinv, N);
    scan2p<<<1, 256, 0, stream>>>(bsums, nbl);
    scan3<<<nbl, 256, 0, stream>>>(rowstart, bsums, N);
    fill_csr<<<ebl, 256, 0, stream>>>(ei, rowstart, cursor, csr, E);

    // dtype prep: covers N_PAD rows, zero-filling pad rows
    {
        size_t n4 = (size_t)N_PAD * D / 4;
        size_t nsrc4 = (size_t)N * D / 4;
        cvt_bf16<<<(int)((n4 + 255) / 256), 256, 0, stream>>>(x, B1, n4, nsrc4);
    }
    WP wp;
    wp.w[0] = W1l; wp.wf[0] = Wf1;
    wp.w[1] = W1r; wp.wf[1] = Wf1 + WFRAG;
    wp.w[2] = W2l; wp.wf[2] = Wf2;
    wp.w[3] = W2r; wp.wf[3] = Wf2 + WFRAG;
    wp.w[4] = W3;  wp.wf[4] = Wf3;
    wfrag_prep<<<dim3(128, 5), 64, 0, stream>>>(wp);

    const int gmm = N_PAD / 128;   // 782 blocks

    // conv1: h1 = relu(mean(x)@W1l + x@W1r + b1)   [agg fused into conv]
    fused_conv<<<gmm, 256, 0, stream>>>(B1, csr, rowstart, deg, dinv, Wf1, b1, B3);
    // conv2: h2 = relu(mean(h1)@W2l + h1@W2r + b2) [B3 pad rows are exact 0]
    fused_conv<<<gmm, 256, 0, stream>>>(B3, csr, rowstart, deg, dinv, Wf2, b2, B1);
    // head
    lin_mfma<<<gmm, 256, 0, stream>>>(B1, Wf3, b3, out);
}

// Round 8
// 644.164 us; speedup vs baseline: 1.3130x; 1.3130x over previous
//
#include <hip/hip_runtime.h>
#include <hip/hip_bf16.h>
#include <cstdint>
#include <cstddef>

#define N_NODES 100000
#define N_PAD   100096   // 782 * 128, M padded to block tile
#define D 256

typedef __attribute__((ext_vector_type(8))) short short8;   // 8 bf16 = 4 VGPRs
typedef __attribute__((ext_vector_type(4))) float f32x4;
typedef __attribute__((ext_vector_type(2))) float f32x2;

__device__ __forceinline__ unsigned short f2bf(float f) {
    unsigned int x; __builtin_memcpy(&x, &f, 4);
    unsigned int r = (x + 0x7FFFu + ((x >> 16) & 1u)) >> 16;   // RNE
    return (unsigned short)r;
}

// ---------------- CSR build ----------------

__global__ __launch_bounds__(256) void count_deg(const int* __restrict__ ei,
                                                 int* __restrict__ deg, int E) {
    int e = blockIdx.x * 256 + threadIdx.x;
    if (e < E) atomicAdd(&deg[ei[E + e]], 1);
}

// scan1 also produces dinv
__global__ __launch_bounds__(256) void scan1(const int* __restrict__ deg,
                                             int* __restrict__ rowstart,
                                             int* __restrict__ bsums,
                                             float* __restrict__ dinv, int N) {
    __shared__ int s[256];
    int i = blockIdx.x * 256 + threadIdx.x;
    int v = (i < N) ? deg[i] : 0;
    if (i < N) dinv[i] = 1.0f / fmaxf((float)v, 1.0f);
    s[threadIdx.x] = v;
    __syncthreads();
    for (int d = 1; d < 256; d <<= 1) {
        int t = (threadIdx.x >= d) ? s[threadIdx.x - d] : 0;
        __syncthreads();
        s[threadIdx.x] += t;
        __syncthreads();
    }
    if (i < N) rowstart[i] = s[threadIdx.x] - v;
    if (threadIdx.x == 255) bsums[blockIdx.x] = s[255];
}

__global__ __launch_bounds__(256) void scan2p(int* __restrict__ bsums, int nb) {
    __shared__ int s[256];
    int t = threadIdx.x;
    int base = t * 2;
    int v0 = (base < nb) ? bsums[base] : 0;
    int v1 = (base + 1 < nb) ? bsums[base + 1] : 0;
    int sum = v0 + v1;
    s[t] = sum;
    __syncthreads();
    for (int d = 1; d < 256; d <<= 1) {
        int tv = (t >= d) ? s[t - d] : 0;
        __syncthreads();
        s[t] += tv;
        __syncthreads();
    }
    int excl = s[t] - sum;
    if (base < nb) bsums[base] = excl;
    if (base + 1 < nb) bsums[base + 1] = excl + v0;
}

__global__ __launch_bounds__(256) void scan3(int* __restrict__ rowstart,
                                             const int* __restrict__ bsums, int N) {
    int i = blockIdx.x * 256 + threadIdx.x;
    if (i < N) rowstart[i] += bsums[blockIdx.x];
}

__global__ __launch_bounds__(256) void fill_csr(const int* __restrict__ ei,
                                                const int* __restrict__ rowstart,
                                                int* __restrict__ cursor,
                                                int* __restrict__ csr, int E) {
    int e = blockIdx.x * 256 + threadIdx.x;
    if (e < E) {
        int src = ei[e], dst = ei[E + e];
        int slot = atomicAdd(&cursor[dst], 1);
        csr[rowstart[dst] + slot] = src;
    }
}

// ---------------- dtype prep ----------------

// x f32 -> bf16 (Xb, for GEMM root term) AND fp8 e4m3 (X8, for gather).
// Covers N_PAD rows; pad rows zero-filled in both.
__global__ __launch_bounds__(256) void cvt_dual(const float* __restrict__ src,
                                                unsigned short* __restrict__ dstb,
                                                unsigned char* __restrict__ dst8,
                                                size_t n4, size_t nsrc4) {
    size_t i = (size_t)blockIdx.x * 256 + threadIdx.x;
    if (i >= n4) return;
    ushort4 o = {0, 0, 0, 0};
    unsigned int w8 = 0;
    if (i < nsrc4) {
        float4 v = *(const float4*)(src + i * 4);
        o.x = f2bf(v.x); o.y = f2bf(v.y); o.z = f2bf(v.z); o.w = f2bf(v.w);
        int w = __builtin_amdgcn_cvt_pk_fp8_f32(v.x, v.y, 0, false);
        w = __builtin_amdgcn_cvt_pk_fp8_f32(v.z, v.w, w, true);
        w8 = (unsigned int)w;
    }
    *(ushort4*)(dstb + i * 4) = o;
    *(unsigned int*)(dst8 + i * 4) = w8;
}

// W [K=256][N=256] f32 -> fragment-ordered bf16, 5 matrices in one launch.
struct WP {
    const float* w[5];
    unsigned short* wf[5];
};
__global__ __launch_bounds__(64) void wfrag_prep(WP wp) {
    const float* __restrict__ W = wp.w[blockIdx.y];
    unsigned short* __restrict__ Wf = wp.wf[blockIdx.y];
    int g = blockIdx.x;              // 0..127: kc*16 + ct
    int lane = threadIdx.x;
    int m = lane & 15, q = lane >> 4;
    int ct = g & 15, kc = g >> 4;
    int n = ct * 16 + m;
    int k0 = kc * 32 + q * 8;
    unsigned short v[8];
#pragma unroll
    for (int j = 0; j < 8; j++) v[j] = f2bf(W[(size_t)(k0 + j) * D + n]);
    *(short8*)(Wf + ((size_t)g * 64 + lane) * 8) = *(short8*)v;
}

// ---------------- aggregation: one wave per node, fp8 gather, bf16 mean out --
// Paired-row: lanes 0-31 read row sA, 32-63 row sB; 8 fp8/lane (uint2, 8 B)
// -> 512 B per paired load. HW cvt_pk_f32_fp8 decode. Same proven structure
// as the bf16 gather; half the serving bytes/lines at the L2-miss tier.

__device__ __forceinline__ void accf8(float* acc, uint2 v) {
    f32x2 a = __builtin_amdgcn_cvt_pk_f32_fp8(v.x, false);
    f32x2 b = __builtin_amdgcn_cvt_pk_f32_fp8(v.x, true);
    f32x2 c = __builtin_amdgcn_cvt_pk_f32_fp8(v.y, false);
    f32x2 d = __builtin_amdgcn_cvt_pk_f32_fp8(v.y, true);
    acc[0] += a[0]; acc[1] += a[1]; acc[2] += b[0]; acc[3] += b[1];
    acc[4] += c[0]; acc[5] += c[1]; acc[6] += d[0]; acc[7] += d[1];
}

__global__ __launch_bounds__(256) void agg_fp8(const unsigned char* __restrict__ X8,
                                               const int* __restrict__ csr,
                                               const int* __restrict__ rowstart,
                                               const int* __restrict__ deg,
                                               const float* __restrict__ dinv,
                                               unsigned short* __restrict__ outb) {
    int node = blockIdx.x * 4 + (threadIdx.x >> 6);
    int l = threadIdx.x & 63;
    int hi = l >> 5;                 // 0 = A-side row, 1 = B-side row
    int boff = (l & 31) * 8;         // bytes: 8 fp8 per lane, 32 lanes = 256 B row
    int start = __builtin_amdgcn_readfirstlane(rowstart[node]);
    int cnt   = __builtin_amdgcn_readfirstlane(deg[node]);
    const unsigned char* xb = X8 + boff;

    float acc[8];
#pragma unroll
    for (int i = 0; i < 8; i++) acc[i] = 0.f;

    int j = 0;
    for (; j + 16 <= cnt; j += 16) {
        uint2 v[8];
#pragma unroll
        for (int p = 0; p < 8; p++) {
            int sA = csr[start + j + 2 * p];
            int sB = csr[start + j + 2 * p + 1];
            int s = hi ? sB : sA;
            v[p] = *(const uint2*)(xb + (size_t)s * 256);
        }
#pragma unroll
        for (int p = 0; p < 8; p++) accf8(acc, v[p]);
    }
    int cm1 = (cnt > 0) ? (cnt - 1) : 0;   // clamp: never index csr[-1]
    for (; j < cnt; j += 8) {
        uint2 v[4];
#pragma unroll
        for (int p = 0; p < 4; p++) {
            int i0 = j + 2 * p;
            int i1 = i0 + 1;
            int sA = csr[start + (i0 < cnt ? i0 : cm1)];
            int sB = csr[start + (i1 < cnt ? i1 : cm1)];
            sA = (i0 < cnt) ? sA : N_NODES;   // row N_NODES is all-zero
            sB = (i1 < cnt) ? sB : N_NODES;
            int s = hi ? sB : sA;
            v[p] = *(const uint2*)(xb + (size_t)s * 256);
        }
#pragma unroll
        for (int p = 0; p < 4; p++) accf8(acc, v[p]);
    }
#pragma unroll
    for (int i = 0; i < 8; i++) acc[i] += __shfl_xor(acc[i], 32);
    if (l < 32) {
        float s = dinv[node];
        uint4 o;
        o.x = (unsigned int)f2bf(acc[0] * s) | ((unsigned int)f2bf(acc[1] * s) << 16);
        o.y = (unsigned int)f2bf(acc[2] * s) | ((unsigned int)f2bf(acc[3] * s) << 16);
        o.z = (unsigned int)f2bf(acc[4] * s) | ((unsigned int)f2bf(acc[5] * s) << 16);
        o.w = (unsigned int)f2bf(acc[6] * s) | ((unsigned int)f2bf(acc[7] * s) << 16);
        *(uint4*)(outb + (size_t)node * D + (l & 31) * 8) = o;
    }
}

// ---------------- block-tiled fused SAGE conv (64x128 wave-tiles) ----------
// out = relu([Am | X] @ Wf + b). r6-proven 2-buffer __syncthreads schedule.
// Optionally dual-writes fp8 e4m3 copy of the output (for the next gather).

#define STAGE(kc, buf)                                                          \
    {                                                                           \
        const unsigned short* gk = Wf + (size_t)(kc) * 8192;                    \
        _Pragma("unroll")                                                       \
        for (int i_ = 0; i_ < 4; i_++) {                                        \
            __builtin_amdgcn_global_load_lds(                                   \
                (const __attribute__((address_space(1))) unsigned int*)         \
                    (gk + (i_ * 256 + tid) * 8),                                \
                (__attribute__((address_space(3))) unsigned int*)               \
                    (&lds[buf][(i_ * 256 + (tid & 192)) * 8]),                  \
                16, 0, 0);                                                      \
        }                                                                       \
    }

__global__ __launch_bounds__(256) void conv_mfma(const unsigned short* __restrict__ Am,
                                                 const unsigned short* __restrict__ X,
                                                 const unsigned short* __restrict__ Wf,
                                                 const float* __restrict__ bias,
                                                 unsigned short* __restrict__ outb,
                                                 unsigned char* __restrict__ out8) {
    __shared__ unsigned short lds[2][8192];   // 2 x 16 KB
    int tid = threadIdx.x;
    int lane = tid & 63;
    int m = lane & 15, q = lane >> 4;
    int wid = tid >> 6;
    int wr = wid >> 1, wc = wid & 1;            // 2x2 wave grid
    int rowb = blockIdx.x * 128 + wr * 64;      // wave's 64-row base
    int ctb = wc * 8;                           // wave's 8 ct-tiles (128 cols)

    f32x4 acc[4][8];
#pragma unroll
    for (int f = 0; f < 4; f++)
#pragma unroll
        for (int ct = 0; ct < 8; ct++) acc[f][ct] = (f32x4){0.f, 0.f, 0.f, 0.f};

    STAGE(0, 0);
    for (int kc = 0; kc < 16; kc++) {
        __syncthreads();                       // stage(kc) landed; buf free
        if (kc < 15) STAGE(kc + 1, (kc + 1) & 1);
        const unsigned short* Asrc = (kc < 8) ? Am : X;
        int koff = (kc & 7) * 32 + q * 8;
        short8 a[4];
#pragma unroll
        for (int f = 0; f < 4; f++)
            a[f] = *(const short8*)(Asrc + (size_t)(rowb + f * 16 + m) * D + koff);
        const unsigned short* lb = lds[kc & 1];
#pragma unroll
        for (int ct = 0; ct < 8; ct++) {
            short8 b = *(const short8*)(lb + ((size_t)(ctb + ct) * 64 + lane) * 8);
#pragma unroll
            for (int f = 0; f < 4; f++)
                acc[f][ct] = __builtin_amdgcn_mfma_f32_16x16x32_bf16(a[f], b, acc[f][ct], 0, 0, 0);
        }
    }
#pragma unroll
    for (int f = 0; f < 4; f++)
#pragma unroll
        for (int ct = 0; ct < 8; ct++) {
            float bb = bias[(ctb + ct) * 16 + m];
#pragma unroll
            for (int r = 0; r < 4; r++) {
                int row = rowb + f * 16 + q * 4 + r;
                int col = (ctb + ct) * 16 + m;
                float rl = (row < N_NODES) ? fmaxf(acc[f][ct][r] + bb, 0.f) : 0.f;
                outb[(size_t)row * D + col] = f2bf(rl);   // pad rows exact 0
                if (out8) {
                    int e8 = __builtin_amdgcn_cvt_pk_fp8_f32(rl, rl, 0, false);
                    out8[(size_t)row * 256 + col] = (unsigned char)(e8 & 0xff);
                }
            }
        }
}

// final linear: out = A @ Wf + b, f32 out, store-guarded to N_NODES, no relu
__global__ __launch_bounds__(256) void lin_mfma(const unsigned short* __restrict__ A,
                                                const unsigned short* __restrict__ Wf,
                                                const float* __restrict__ bias,
                                                float* __restrict__ out) {
    __shared__ unsigned short lds[2][8192];
    int tid = threadIdx.x;
    int lane = tid & 63;
    int m = lane & 15, q = lane >> 4;
    int wid = tid >> 6;
    int wr = wid >> 1, wc = wid & 1;
    int rowb = blockIdx.x * 128 + wr * 64;
    int ctb = wc * 8;

    f32x4 acc[4][8];
#pragma unroll
    for (int f = 0; f < 4; f++)
#pragma unroll
        for (int ct = 0; ct < 8; ct++) acc[f][ct] = (f32x4){0.f, 0.f, 0.f, 0.f};

    STAGE(0, 0);
    for (int kc = 0; kc < 8; kc++) {
        __syncthreads();
        if (kc < 7) STAGE(kc + 1, (kc + 1) & 1);
        int koff = kc * 32 + q * 8;
        short8 a[4];
#pragma unroll
        for (int f = 0; f < 4; f++)
            a[f] = *(const short8*)(A + (size_t)(rowb + f * 16 + m) * D + koff);
        const unsigned short* lb = lds[kc & 1];
#pragma unroll
        for (int ct = 0; ct < 8; ct++) {
            short8 b = *(const short8*)(lb + ((size_t)(ctb + ct) * 64 + lane) * 8);
#pragma unroll
            for (int f = 0; f < 4; f++)
                acc[f][ct] = __builtin_amdgcn_mfma_f32_16x16x32_bf16(a[f], b, acc[f][ct], 0, 0, 0);
        }
    }
#pragma unroll
    for (int f = 0; f < 4; f++)
#pragma unroll
        for (int ct = 0; ct < 8; ct++) {
            float bb = bias[(ctb + ct) * 16 + m];
#pragma unroll
            for (int r = 0; r < 4; r++) {
                int row = rowb + f * 16 + q * 4 + r;
                if (row < N_NODES)
                    out[(size_t)row * D + (ctb + ct) * 16 + m] = acc[f][ct][r] + bb;
            }
        }
}

// ---------------- launch ----------------

extern "C" void kernel_launch(void* const* d_in, const int* in_sizes, int n_in,
                              void* d_out, int out_size, void* d_ws, size_t ws_size,
                              hipStream_t stream) {
    const float* x   = (const float*)d_in[0];
    const int*   ei  = (const int*)d_in[1];
    const float* W1l = (const float*)d_in[2];
    const float* b1  = (const float*)d_in[3];
    const float* W1r = (const float*)d_in[4];
    const float* W2l = (const float*)d_in[5];
    const float* b2  = (const float*)d_in[6];
    const float* W2r = (const float*)d_in[7];
    const float* W3  = (const float*)d_in[8];
    const float* b3  = (const float*)d_in[9];
    float* out = (float*)d_out;

    const int N = N_NODES;
    const int E = in_sizes[1] / 2;
    const size_t FB = (size_t)N_PAD * D * sizeof(unsigned short);   // 51.25 MB
    const size_t WFRAG = (size_t)128 * 64 * 8;   // shorts per 256-K half

    char* p = (char*)d_ws;
    unsigned short* B1 = (unsigned short*)p; p += FB;   // xb, then conv2 out (h2)
    unsigned short* B2 = (unsigned short*)p; p += FB;   // agg out (mean)
    unsigned short* B3 = (unsigned short*)p; p += FB;   // conv1 out (h1)
    unsigned short* Wf1 = (unsigned short*)p; p += WFRAG * 2 * 2;   // [W1l | W1r]
    unsigned short* Wf2 = (unsigned short*)p; p += WFRAG * 2 * 2;
    unsigned short* Wf3 = (unsigned short*)p; p += WFRAG * 2;
    int*   deg      = (int*)p;   p += (size_t)N * 4;
    int*   cursor   = (int*)p;   p += (size_t)N * 4;   // adjacent to deg: one memset
    float* dinv     = (float*)p; p += (size_t)N * 4;
    int*   rowstart = (int*)p;   p += (size_t)N * 4;
    int*   bsums    = (int*)p;   p += 4096;
    int*   csr      = (int*)p;   p += (size_t)E * 4;
    unsigned char* G8 = (unsigned char*)p; p += (size_t)N_PAD * 256;  // fp8 x, then fp8 h1

    hipMemsetAsync(deg, 0, (size_t)N * 8, stream);   // deg + cursor in one shot

    int ebl = (E + 255) / 256;
    int nbl = (N + 255) / 256;

    // CSR
    count_deg<<<ebl, 256, 0, stream>>>(ei, deg, E);
    scan1<<<nbl, 256, 0, stream>>>(deg, rowstart, bsums, dinv, N);
    scan2p<<<1, 256, 0, stream>>>(bsums, nbl);
    scan3<<<nbl, 256, 0, stream>>>(rowstart, bsums, N);
    fill_csr<<<ebl, 256, 0, stream>>>(ei, rowstart, cursor, csr, E);

    // dtype prep: bf16 + fp8, pad rows zero-filled
    {
        size_t n4 = (size_t)N_PAD * D / 4;
        size_t nsrc4 = (size_t)N * D / 4;
        cvt_dual<<<(int)((n4 + 255) / 256), 256, 0, stream>>>(x, B1, G8, n4, nsrc4);
    }
    WP wp;
    wp.w[0] = W1l; wp.wf[0] = Wf1;
    wp.w[1] = W1r; wp.wf[1] = Wf1 + WFRAG;
    wp.w[2] = W2l; wp.wf[2] = Wf2;
    wp.w[3] = W2r; wp.wf[3] = Wf2 + WFRAG;
    wp.w[4] = W3;  wp.wf[4] = Wf3;
    wfrag_prep<<<dim3(128, 5), 64, 0, stream>>>(wp);

    const int gmm = N_PAD / 128;   // 782 blocks

    // conv1: h1 = relu(mean(x)@W1l + x@W1r + b1); dual-writes fp8(h1) into G8
    agg_fp8<<<N / 4, 256, 0, stream>>>(G8, csr, rowstart, deg, dinv, B2);
    conv_mfma<<<gmm, 256, 0, stream>>>(B2, B1, Wf1, b1, B3, G8);
    // conv2: h2 = relu(mean(h1)@W2l + h1@W2r + b2)
    agg_fp8<<<N / 4, 256, 0, stream>>>(G8, csr, rowstart, deg, dinv, B2);
    conv_mfma<<<gmm, 256, 0, stream>>>(B2, B3, Wf2, b2, B1, (unsigned char*)nullptr);
    // head
    lin_mfma<<<gmm, 256, 0, stream>>>(B1, Wf3, b3, out);
}